// Round 5
// baseline (1515.488 us; speedup 1.0000x reference)
//
#include <hip/hip_runtime.h>

using u32 = unsigned int;

constexpr int B = 131072;
constexpr int K = 512;
constexpr int D = 128;
constexpr int RPB = 64;       // rows per block
constexpr int RG  = 8;        // rows per epilogue group
constexpr int NG  = RPB / RG; // groups per block
constexpr int CH  = 4;        // float4 steps per E-chunk (16 d's)
constexpr int NCH = (D / 4) / CH; // 8 chunks
constexpr float SMBETA = 10.0f;

// flat f32-element offsets into d_out (return order)
constexpr size_t OFF_Q    = 0;
constexpr size_t OFF_VQ   = (size_t)B * D;            // 16777216
constexpr size_t OFF_ENT  = OFF_VQ + 1;               // 16777217
constexpr size_t OFF_INDS = OFF_VQ + 2;               // 16777218
constexpr size_t OFF_SOFT = OFF_INDS + (size_t)B;     // 16908290
constexpr size_t OFF_CL   = OFF_SOFT + (size_t)B * K; // 84017154

// amdgpu_waves_per_eu(2,2): pin the scheduler's occupancy TARGET (not just the
// floor) at 2 waves/EU -> 256-VGPR budget, no pressure-driven sinking/spill.
// R4 evidence: __launch_bounds__(512,2) is only a FLOOR — the backend still
// targeted ~6 waves/EU and allocated 88 VGPR, spilling acc[64] (FETCH +34MB,
// WRITE +33MB, VALU-busy +1.7x). This attribute is the whole experiment.
__global__ __launch_bounds__(512)
__attribute__((amdgpu_waves_per_eu(2, 2)))
void vq_main(
    const float* __restrict__ X, const float* __restrict__ E,
    float* __restrict__ out,
    u32* __restrict__ counts,
    float* __restrict__ sse_g, float* __restrict__ clus_g)
{
  __shared__ float gbuf[RG][K];   // 16 KiB: d values, then p~ values (per epilogue group)
  __shared__ float sx_sh[RPB];    // sx for all 64 rows of the block
  __shared__ float m_sh[RG];
  __shared__ int   amin_sh[RG];
  __shared__ float invS_sh[RG];
  __shared__ float red_sh[16];

  const int tid  = threadIdx.x;
  const int j    = tid;          // code index, 0..511
  const int w    = tid >> 6;     // wave id 0..7
  const int lane = tid & 63;
  const int row0 = blockIdx.x * RPB;

  // ---- sx for all 64 rows up front (f32 squares, f64 shuffle-tree sum, RN f32 —
  // bit-identical per-row arithmetic to the proven per-group version) ----
  #pragma unroll 1
  for (int t = 0; t < NG; ++t) {
    const int rr = t * RG + w;           // same wave->row assignment as old gi loop
    const float* xr = X + (size_t)(row0 + rr) * D;
    float v0 = xr[lane], v1 = xr[lane + 64];
    float s0 = v0 * v0, s1 = v1 * v1;
    double tt = (double)s0 + (double)s1;
    for (int mk = 1; mk < 64; mk <<= 1) tt += __shfl_xor(tt, mk, 64);
    if (lane == 0) sx_sh[rr] = (float)tt;
  }
  __syncthreads();

  // ---- dot(x_r, e_j) for ALL 64 rows at once. acc[64] is accumulator state;
  // with the 2-waves/EU target the allocator can finally keep it resident.
  // E read once per thread total (8 chunks x 16 floats). X loads are
  // block-uniform (one line per wave, broadcast). Per (row, code): single f32
  // accumulator, strictly sequential FMA over d ascending (chunks ascend,
  // s ascends within chunk) — bit-identical dist to the proven kernels.
  const float4* xg4 = (const float4*)(X + (size_t)row0 * D);  // block-uniform
  const float4* Ej4 = (const float4*)(E + (size_t)j * D);

  float acc[RPB];
  #pragma unroll
  for (int r = 0; r < RPB; ++r) acc[r] = 0.f;

  // se_j accumulated in the same strictly d-ascending f64 order as before.
  double seD = 0.0;

  #pragma unroll 1
  for (int c = 0; c < NCH; ++c) {
    float4 e4[CH];
    #pragma unroll
    for (int s = 0; s < CH; ++s) e4[s] = Ej4[c * CH + s];

    #pragma unroll
    for (int s = 0; s < CH; ++s) {
      float e0 = e4[s].x; seD += (double)(e0 * e0);
      float e1 = e4[s].y; seD += (double)(e1 * e1);
      float e2 = e4[s].z; seD += (double)(e2 * e2);
      float e3 = e4[s].w; seD += (double)(e3 * e3);
    }

    // s-outer / r-inner: consecutive instructions are independent chains -> full ILP
    #pragma unroll
    for (int s = 0; s < CH; ++s) {
      #pragma unroll
      for (int r = 0; r < RPB; ++r) {
        float4 x4 = xg4[r * 32 + c * CH + s];
        float a = acc[r];
        a = fmaf(e4[s].x, x4.x, a);   // ascending d order, strictly sequential per row
        a = fmaf(e4[s].y, x4.y, a);
        a = fmaf(e4[s].z, x4.z, a);
        a = fmaf(e4[s].w, x4.w, a);
        acc[r] = a;
      }
    }
  }
  const float se = (float)seD;

  // dist in place: dq = RN(RN(sx + se) - 2*dot) — exact replication of np's
  // elementwise f32 ops (the *2 is exact, FMA contraction bit-identical).
  #pragma unroll
  for (int r = 0; r < RPB; ++r) {
    float a = sx_sh[r] + se;
    acc[r] = a - 2.0f * acc[r];
  }

  float sse_l = 0.f, msum_l = 0.f;

  // ---- epilogue: proven per-group pipeline, fully unrolled so acc indexing
  // stays compile-time-static (runtime-indexed reg arrays go to scratch) ----
  #pragma unroll
  for (int gi = 0; gi < NG; ++gi) {
    const int grow0 = row0 + gi * RG;

    #pragma unroll
    for (int r = 0; r < RG; ++r) gbuf[r][j] = acc[gi * RG + r];
    __syncthreads();

    // argmin over quantized dist, FIRST-index tie-break (np.argmin semantics)
    {
      float mv = 3.4e38f; int mi = 0;
      #pragma unroll
      for (int k2 = 0; k2 < 8; ++k2) {
        int jj = lane + 64 * k2;
        float v = gbuf[w][jj];
        if (v < mv || (v == mv && jj < mi)) { mv = v; mi = jj; }
      }
      for (int mk = 1; mk < 64; mk <<= 1) {
        float ov = __shfl_xor(mv, mk, 64);
        int   oi = __shfl_xor(mi, mk, 64);
        if (ov < mv || (ov == mv && oi < mi)) { mv = ov; mi = oi; }
      }
      if (lane == 0) { m_sh[w] = mv; amin_sh[w] = mi; }
    }
    __syncthreads();

    // softmax(-beta * dist), shift-invariant with the row min
    float p[RG];
    #pragma unroll
    for (int r = 0; r < RG; ++r) {
      p[r] = __expf(-SMBETA * (acc[gi * RG + r] - m_sh[r]));
      gbuf[r][j] = p[r];           // safe: d-values consumed before previous barrier
    }
    __syncthreads();

    // row-sum of p~: wave w reduces row w
    {
      float sv = 0.f;
      #pragma unroll
      for (int k2 = 0; k2 < 8; ++k2) sv += gbuf[w][lane + 64 * k2];
      for (int mk = 1; mk < 64; mk <<= 1) sv += __shfl_xor(sv, mk, 64);
      if (lane == 0) invS_sh[w] = 1.f / sv;
    }
    __syncthreads();

    // soft outputs (f32)
    #pragma unroll
    for (int r = 0; r < RG; ++r) {
      size_t row = (size_t)(grow0 + r);
      out[OFF_SOFT + row * K + j] = p[r] * invS_sh[r];
    }

    // per-row outputs: wave w handles row w
    {
      int row = grow0 + w;
      int am  = amin_sh[w];
      const float* xr = X + (size_t)row * D;
      const float* er = E + (size_t)am * D;
      #pragma unroll
      for (int t = 0; t < 2; ++t) {
        int d = lane + 64 * t;
        float xv = xr[d], ev = er[d];
        float df = ev - xv;
        sse_l = fmaf(df, df, sse_l);
        out[OFF_Q + (size_t)row * D + d] = ev;   // bit-exact f32 passthrough of emb row
      }
      if (lane == 0) {
        out[OFF_INDS + row] = (float)am;
        atomicAdd(&counts[am], 1u);
        msum_l += m_sh[w];    // quantized min == ref's dist at argmin (bit-exact)
      }
    }
    __syncthreads();
  }

  // block-reduce loss/cluster partials, one atomic each per block
  for (int mk = 1; mk < 64; mk <<= 1) {
    sse_l  += __shfl_xor(sse_l,  mk, 64);
    msum_l += __shfl_xor(msum_l, mk, 64);
  }
  if (lane == 0) { red_sh[w] = sse_l; red_sh[8 + w] = msum_l; }
  __syncthreads();
  if (tid == 0) {
    float s1 = 0.f, s2 = 0.f;
    for (int q = 0; q < 8; ++q) { s1 += red_sh[q]; s2 += red_sh[8 + q]; }
    atomicAdd(sse_g, s1);
    atomicAdd(clus_g, s2);
  }
}

__global__ __launch_bounds__(512) void vq_final(
    const u32* __restrict__ counts,
    const float* __restrict__ sse_g, const float* __restrict__ clus_g,
    float* __restrict__ out)
{
  __shared__ double part[8];
  const int tid = threadIdx.x, w = tid >> 6, lane = tid & 63;
  double pv = (double)counts[tid] / (double)B;
  double term = -pv * log(pv + 1e-10);
  for (int mk = 1; mk < 64; mk <<= 1) term += __shfl_xor(term, mk, 64);
  if (lane == 0) part[w] = term;
  __syncthreads();
  if (tid == 0) {
    double ent = 0.0;
    for (int q = 0; q < 8; ++q) ent += part[q];
    double sse = (double)*sse_g;
    double vq  = 1.25 * sse / ((double)B * (double)D);  // 0.25*commit + embed (same fwd value)
    double cl  = (double)*clus_g / (double)B;
    out[OFF_VQ]  = (float)vq;
    out[OFF_ENT] = (float)ent;
    out[OFF_CL]  = (float)cl;
  }
}

extern "C" void kernel_launch(void* const* d_in, const int* in_sizes, int n_in,
                              void* d_out, int out_size, void* d_ws, size_t ws_size,
                              hipStream_t stream) {
  const float* X = (const float*)d_in[0];   // latents [131072,128] f32
  const float* E = (const float*)d_in[1];   // emb_weight [512,128] f32
  if (n_in >= 2 && in_sizes[0] == K * D && in_sizes[1] == B * D) {
    const float* t = X; X = E; E = t;       // defensive: inputs swapped
  }
  float* out = (float*)d_out;

  u32*   counts = (u32*)d_ws;                    // 512 * u32
  float* sse_g  = (float*)((char*)d_ws + 2048);
  float* clus_g = (float*)((char*)d_ws + 2052);

  hipMemsetAsync(d_ws, 0, 4096, stream);
  vq_main<<<B / RPB, 512, 0, stream>>>(X, E, out, counts, sse_g, clus_g);
  vq_final<<<1, 512, 0, stream>>>(counts, sse_g, clus_g, out);
}

// Round 6
// 827.138 us; speedup vs baseline: 1.8322x; 1.8322x over previous
//
#include <hip/hip_runtime.h>

using u32 = unsigned int;

constexpr int B = 131072;
constexpr int K = 512;
constexpr int D = 128;
constexpr int RPB = 16;       // rows per block (small acc footprint: allocator-friendly)
constexpr int RG  = 8;        // rows per epilogue group
constexpr int NG  = RPB / RG; // 2 groups per block
constexpr int CH  = 4;        // float4 steps per E-chunk (16 d's)
constexpr int NCH = (D / 4) / CH; // 8 chunks
constexpr float SMBETA = 10.0f;

// flat f32-element offsets into d_out (return order)
constexpr size_t OFF_Q    = 0;
constexpr size_t OFF_VQ   = (size_t)B * D;            // 16777216
constexpr size_t OFF_ENT  = OFF_VQ + 1;               // 16777217
constexpr size_t OFF_INDS = OFF_VQ + 2;               // 16777218
constexpr size_t OFF_SOFT = OFF_INDS + (size_t)B;     // 16908290
constexpr size_t OFF_CL   = OFF_SOFT + (size_t)B * K; // 84017154

// se_j = f32(sum_f64(f32(e*e))), strictly d-ascending — computed ONCE for all
// 512 codes (was per-thread: 128 f64 cvt+add in every hot thread). Bit-identical
// value to the proven in-thread computation.
__global__ void vq_pre(const float* __restrict__ E, float* __restrict__ se_out)
{
  const int j = threadIdx.x;                 // 512 threads, 1 block
  const float* Ej = E + (size_t)j * D;
  double s = 0.0;
  for (int d = 0; d < D; ++d) { float v = Ej[d]; s += (double)(v * v); }
  se_out[j] = (float)s;
}

// RPB=16 design rationale (post-mortem of R3-R5): acc[64]-per-thread forced the
// allocator into AGPR/operand juggling (~3 extra VALU ops per FMA; VALU-issue
// time 586us vs 110us algorithmic) and NO occupancy knob changed its plan.
// acc[16]+e4[4] ~= 48-56 VGPR fits the default 8-waves/EU budget -> 24-32
// waves/CU of TLP to hide the divergent E-row loads (read once per thread).
__global__ __launch_bounds__(512) void vq_main(
    const float* __restrict__ X, const float* __restrict__ E,
    const float* __restrict__ se_pre,
    float* __restrict__ out,
    u32* __restrict__ counts,
    float* __restrict__ sse_g, float* __restrict__ clus_g)
{
  __shared__ float gbuf[RG][K];   // 16 KiB: d values, then p~ values (per epilogue group)
  __shared__ float sx_sh[RPB];    // sx for the 16 rows of the block
  __shared__ float m_sh[RG];
  __shared__ int   amin_sh[RG];
  __shared__ float invS_sh[RG];
  __shared__ float red_sh[16];

  const int tid  = threadIdx.x;
  const int j    = tid;          // code index, 0..511
  const int w    = tid >> 6;     // wave id 0..7
  const int lane = tid & 63;
  const int row0 = blockIdx.x * RPB;

  const float se = se_pre[j];    // coalesced (lane j -> word j)

  // ---- sx for the 16 rows up front (f32 squares, f64 shuffle-tree sum, RN f32 —
  // bit-identical per-row arithmetic to the proven per-group version) ----
  #pragma unroll 1
  for (int t = 0; t < NG; ++t) {
    const int rr = t * RG + w;           // same wave->row assignment as the old gi loop
    const float* xr = X + (size_t)(row0 + rr) * D;
    float v0 = xr[lane], v1 = xr[lane + 64];
    float s0 = v0 * v0, s1 = v1 * v1;
    double tt = (double)s0 + (double)s1;
    for (int mk = 1; mk < 64; mk <<= 1) tt += __shfl_xor(tt, mk, 64);
    if (lane == 0) sx_sh[rr] = (float)tt;
  }
  __syncthreads();

  // ---- dot(x_r, e_j) for the 16 rows. E read once per thread total (8 chunks
  // x 16 floats, divergent but L2-resident). X loads are block-uniform ->
  // scalar s_load path shared by all 8 waves. Per (row, code): single f32
  // accumulator, strictly sequential FMA over d ascending (chunks ascend,
  // s ascends within chunk, x/y/z/w in order) — bit-identical dist.
  const float4* xg4 = (const float4*)(X + (size_t)row0 * D);  // block-uniform
  const float4* Ej4 = (const float4*)(E + (size_t)j * D);

  float acc[RPB];
  #pragma unroll
  for (int r = 0; r < RPB; ++r) acc[r] = 0.f;

  #pragma unroll 1
  for (int c = 0; c < NCH; ++c) {
    float4 e4[CH];
    #pragma unroll
    for (int s = 0; s < CH; ++s) e4[s] = Ej4[c * CH + s];

    // s-outer / r-inner: consecutive instructions are independent chains -> full ILP
    #pragma unroll
    for (int s = 0; s < CH; ++s) {
      #pragma unroll
      for (int r = 0; r < RPB; ++r) {
        float4 x4 = xg4[r * 32 + c * CH + s];
        float a = acc[r];
        a = fmaf(e4[s].x, x4.x, a);   // ascending d order, strictly sequential per row
        a = fmaf(e4[s].y, x4.y, a);
        a = fmaf(e4[s].z, x4.z, a);
        a = fmaf(e4[s].w, x4.w, a);
        acc[r] = a;
      }
    }
  }

  // dist in place: dq = RN(RN(sx + se) - 2*dot) — exact replication of np's
  // elementwise f32 ops (the *2 is exact, FMA contraction bit-identical).
  #pragma unroll
  for (int r = 0; r < RPB; ++r) {
    float a = sx_sh[r] + se;
    acc[r] = a - 2.0f * acc[r];
  }

  float sse_l = 0.f, msum_l = 0.f;

  // ---- epilogue: proven per-group pipeline, fully unrolled so acc indexing
  // stays compile-time-static (runtime-indexed reg arrays go to scratch) ----
  #pragma unroll
  for (int gi = 0; gi < NG; ++gi) {
    const int grow0 = row0 + gi * RG;

    #pragma unroll
    for (int r = 0; r < RG; ++r) gbuf[r][j] = acc[gi * RG + r];
    __syncthreads();

    // argmin over quantized dist, FIRST-index tie-break (np.argmin semantics)
    {
      float mv = 3.4e38f; int mi = 0;
      #pragma unroll
      for (int k2 = 0; k2 < 8; ++k2) {
        int jj = lane + 64 * k2;
        float v = gbuf[w][jj];
        if (v < mv || (v == mv && jj < mi)) { mv = v; mi = jj; }
      }
      for (int mk = 1; mk < 64; mk <<= 1) {
        float ov = __shfl_xor(mv, mk, 64);
        int   oi = __shfl_xor(mi, mk, 64);
        if (ov < mv || (ov == mv && oi < mi)) { mv = ov; mi = oi; }
      }
      if (lane == 0) { m_sh[w] = mv; amin_sh[w] = mi; }
    }
    __syncthreads();

    // softmax(-beta * dist), shift-invariant with the row min
    float p[RG];
    #pragma unroll
    for (int r = 0; r < RG; ++r) {
      p[r] = __expf(-SMBETA * (acc[gi * RG + r] - m_sh[r]));
      gbuf[r][j] = p[r];           // safe: d-values consumed before previous barrier
    }
    __syncthreads();

    // row-sum of p~: wave w reduces row w
    {
      float sv = 0.f;
      #pragma unroll
      for (int k2 = 0; k2 < 8; ++k2) sv += gbuf[w][lane + 64 * k2];
      for (int mk = 1; mk < 64; mk <<= 1) sv += __shfl_xor(sv, mk, 64);
      if (lane == 0) invS_sh[w] = 1.f / sv;
    }
    __syncthreads();

    // soft outputs (f32)
    #pragma unroll
    for (int r = 0; r < RG; ++r) {
      size_t row = (size_t)(grow0 + r);
      out[OFF_SOFT + row * K + j] = p[r] * invS_sh[r];
    }

    // per-row outputs: wave w handles row w
    {
      int row = grow0 + w;
      int am  = amin_sh[w];
      const float* xr = X + (size_t)row * D;
      const float* er = E + (size_t)am * D;
      #pragma unroll
      for (int t = 0; t < 2; ++t) {
        int d = lane + 64 * t;
        float xv = xr[d], ev = er[d];
        float df = ev - xv;
        sse_l = fmaf(df, df, sse_l);
        out[OFF_Q + (size_t)row * D + d] = ev;   // bit-exact f32 passthrough of emb row
      }
      if (lane == 0) {
        out[OFF_INDS + row] = (float)am;
        atomicAdd(&counts[am], 1u);
        msum_l += m_sh[w];    // quantized min == ref's dist at argmin (bit-exact)
      }
    }
    __syncthreads();
  }

  // block-reduce loss/cluster partials, one atomic each per block
  for (int mk = 1; mk < 64; mk <<= 1) {
    sse_l  += __shfl_xor(sse_l,  mk, 64);
    msum_l += __shfl_xor(msum_l, mk, 64);
  }
  if (lane == 0) { red_sh[w] = sse_l; red_sh[8 + w] = msum_l; }
  __syncthreads();
  if (tid == 0) {
    float s1 = 0.f, s2 = 0.f;
    for (int q = 0; q < 8; ++q) { s1 += red_sh[q]; s2 += red_sh[8 + q]; }
    atomicAdd(sse_g, s1);
    atomicAdd(clus_g, s2);
  }
}

__global__ __launch_bounds__(512) void vq_final(
    const u32* __restrict__ counts,
    const float* __restrict__ sse_g, const float* __restrict__ clus_g,
    float* __restrict__ out)
{
  __shared__ double part[8];
  const int tid = threadIdx.x, w = tid >> 6, lane = tid & 63;
  double pv = (double)counts[tid] / (double)B;
  double term = -pv * log(pv + 1e-10);
  for (int mk = 1; mk < 64; mk <<= 1) term += __shfl_xor(term, mk, 64);
  if (lane == 0) part[w] = term;
  __syncthreads();
  if (tid == 0) {
    double ent = 0.0;
    for (int q = 0; q < 8; ++q) ent += part[q];
    double sse = (double)*sse_g;
    double vq  = 1.25 * sse / ((double)B * (double)D);  // 0.25*commit + embed (same fwd value)
    double cl  = (double)*clus_g / (double)B;
    out[OFF_VQ]  = (float)vq;
    out[OFF_ENT] = (float)ent;
    out[OFF_CL]  = (float)cl;
  }
}

extern "C" void kernel_launch(void* const* d_in, const int* in_sizes, int n_in,
                              void* d_out, int out_size, void* d_ws, size_t ws_size,
                              hipStream_t stream) {
  const float* X = (const float*)d_in[0];   // latents [131072,128] f32
  const float* E = (const float*)d_in[1];   // emb_weight [512,128] f32
  if (n_in >= 2 && in_sizes[0] == K * D && in_sizes[1] == B * D) {
    const float* t = X; X = E; E = t;       // defensive: inputs swapped
  }
  float* out = (float*)d_out;

  u32*   counts = (u32*)d_ws;                    // 512 * u32
  float* sse_g  = (float*)((char*)d_ws + 2048);
  float* clus_g = (float*)((char*)d_ws + 2052);
  float* se_ws  = (float*)((char*)d_ws + 4096);  // 512 * f32

  hipMemsetAsync(d_ws, 0, 4096, stream);
  vq_pre<<<1, 512, 0, stream>>>(E, se_ws);
  vq_main<<<B / RPB, 512, 0, stream>>>(X, E, se_ws, out, counts, sse_g, clus_g);
  vq_final<<<1, 512, 0, stream>>>(counts, sse_g, clus_g, out);
}